// Round 23
// baseline (1603.507 us; speedup 1.0000x reference)
//
#include <hip/hip_runtime.h>
#include <hip/hip_bf16.h>

#define L_   2048
#define NB_  512
#define HID_ 1024
#define H_   16
#define D_   64
#define B_   8
#define Q_   2048

typedef unsigned short u16;
typedef float  f32x4  __attribute__((ext_vector_type(4)));
typedef short  short8 __attribute__((ext_vector_type(8)));

__device__ __forceinline__ u16 f2b_f23(float x) {
    __hip_bfloat16 h = __float2bfloat16(x);
    union { __hip_bfloat16 h; u16 u; } cv; cv.h = h; return cv.u;
}
__device__ __forceinline__ float b2f_f23(u16 u) {
    union { u16 u; __hip_bfloat16 h; } cv; cv.u = u; return __bfloat162float(cv.h);
}
__device__ __forceinline__ float ldin_f23(const void* p, long i, int bf) {
    return bf ? b2f_f23(((const u16*)p)[i]) : ((const float*)p)[i];
}

#define GLDSF23(gp, lp) __builtin_amdgcn_global_load_lds( \
    (const __attribute__((address_space(1))) void*)(gp), \
    (__attribute__((address_space(3))) void*)(lp), 16, 0, 0)

// ---------------------------------------------------------------------------
__global__ void probe_f23(const unsigned* __restrict__ k, int* __restrict__ flag)
{
    __shared__ int cnt;
    if (threadIdx.x == 0) cnt = 0;
    __syncthreads();
    int c = 0;
    for (int i = threadIdx.x; i < 4096; i += 256) {
        unsigned e = (k[i] >> 7) & 0xFFu;
        if (e >= 100u && e <= 135u) c++;
    }
    atomicAdd(&cnt, c);
    __syncthreads();
    if (threadIdx.x == 0) *flag = (cnt > 2048) ? 1 : 0;
}

__global__ void beacon_f23(float* __restrict__ out, long n, float code)
{
    long i = (long)blockIdx.x * blockDim.x + threadIdx.x;
    long st = (long)gridDim.x * blockDim.x;
    for (; i < n; i += st) out[i] = 0.f;
    if (blockIdx.x == 0 && threadIdx.x == 0) out[0] = code;
}

// ---------------------------------------------------------------------------
__global__ void conv_f23(const void* __restrict__ in, u16* __restrict__ out,
                         long n, const int* __restrict__ dflag)
{
    const int bf = *dflag;
    long i = (long)blockIdx.x * blockDim.x + threadIdx.x;
    long st = (long)gridDim.x * blockDim.x;
    for (; i < n; i += st) out[i] = f2b_f23(ldin_f23(in, i, bf));
}

// query (B,H,Q,64) -> qflat (B,Q,HID) bf16
__global__ void qg_f23(const void* __restrict__ q, u16* __restrict__ out,
                       const int* __restrict__ dflag)
{
    const int bf = *dflag;
    const long n = (long)B_ * H_ * Q_ * D_;
    long i = (long)blockIdx.x * blockDim.x + threadIdx.x;
    long st = (long)gridDim.x * blockDim.x;
    for (; i < n; i += st) {
        long dd = i & 63; long t = i >> 6;
        long qq = t & (Q_ - 1); t >>= 11;
        long h = t & (H_ - 1); long b = t >> 4;
        out[(b * Q_ + qq) * HID_ + h * 64 + dd] = f2b_f23(ldin_f23(q, i, bf));
    }
}

// fp32 -> hi + lo residual (bf16)   [proven]
__global__ void split_f23(const float* __restrict__ in, u16* __restrict__ hi,
                          u16* __restrict__ lo, long n)
{
    long i = (long)blockIdx.x * blockDim.x + threadIdx.x;
    long st = (long)gridDim.x * blockDim.x;
    for (; i < n; i += st) {
        float v = in[i];
        u16 h = f2b_f23(v);
        hi[i] = h;
        lo[i] = f2b_f23(v - b2f_f23(h));
    }
}

// transpose (proven): in (R,C) raw -> out (C,R) bf16
__global__ __launch_bounds__(256)
void tr_f23(const void* __restrict__ in, u16* __restrict__ out,
            int R, int C, long sIn, long sOut, const int* __restrict__ dflag)
{
    const int bf = *dflag;
    __shared__ u16 t[64][66];
    const long ibase = (long)blockIdx.z * sIn;
    u16* ob = out + (long)blockIdx.z * sOut;
    const int r0 = blockIdx.y * 64, c0 = blockIdx.x * 64;
    const int lc = threadIdx.x & 63, rb = threadIdx.x >> 6;
    #pragma unroll
    for (int kk = 0; kk < 16; ++kk) {
        int r = rb * 16 + kk;
        t[r][lc] = f2b_f23(ldin_f23(in, ibase + (long)(r0 + r) * C + c0 + lc, bf));
    }
    __syncthreads();
    #pragma unroll
    for (int kk = 0; kk < 16; ++kk) {
        int cr = rb * 16 + kk;
        ob[(long)(c0 + cr) * R + r0 + lc] = t[lc][cr];
    }
}

// elementwise mask epilogue (proven): km = kT * sigmoid(S + bmask), in place
__global__ void ew_f23(float* __restrict__ S, const u16* __restrict__ kT,
                       const void* __restrict__ bmask, const int* __restrict__ dflag)
{
    const int bf = *dflag;
    const long n = (long)B_ * HID_ * L_;
    long i = (long)blockIdx.x * blockDim.x + threadIdx.x;
    long st = (long)gridDim.x * blockDim.x;
    for (; i < n; i += st) {
        long m = i & (L_ - 1);
        float sg = 1.f / (1.f + expf(-(S[i] + ldin_f23(bmask, m, bf))));
        S[i] = b2f_f23(kT[i]) * sg;
    }
}

// ---------------------------------------------------------------------------
// MFMA GEMM (m97 structure, proven): C[M,N] = sum_k A[M,K]*Bt[N,K]
// epi: 3 = fp32 store (scale applied) ; 4 = fp32 accumulate
// ---------------------------------------------------------------------------
__global__ __launch_bounds__(256)
void gemm_f23(const u16* __restrict__ A, int lda, long sA,
              const u16* __restrict__ Bt, int ldb, long sB,
              float* __restrict__ Cv, int ldc, long sC, int K,
              float scale, int epi)
{
    __shared__ u16 As[128 * 32];
    __shared__ u16 Bs[128 * 32];
    const int tid = threadIdx.x;
    const int wv = tid >> 6, ln = tid & 63;
    const int g = ln >> 4, lr = ln & 15;
    const int wr = wv >> 1, wc = wv & 1;
    const int bm = blockIdx.y * 128, bn = blockIdx.x * 128;
    const u16* Ab = A + (long)blockIdx.z * sA;
    const u16* Bb = Bt + (long)blockIdx.z * sB;

    const int sr = ln >> 2;
    const int scl = (ln & 3) * 8;
    const u16* ga0 = Ab + (long)(bm + wv * 16 + sr) * lda + scl;
    const u16* ga1 = Ab + (long)(bm + (wv + 4) * 16 + sr) * lda + scl;
    const u16* gb0 = Bb + (long)(bn + wv * 16 + sr) * ldb + scl;
    const u16* gb1 = Bb + (long)(bn + (wv + 4) * 16 + sr) * ldb + scl;
    u16* la0 = &As[wv * 512];
    u16* la1 = &As[(wv + 4) * 512];
    u16* lb0 = &Bs[wv * 512];
    u16* lb1 = &Bs[(wv + 4) * 512];

    f32x4 acc[4][4];
    #pragma unroll
    for (int i = 0; i < 4; ++i)
        #pragma unroll
        for (int j = 0; j < 4; ++j) acc[i][j] = (f32x4){0.f, 0.f, 0.f, 0.f};

    for (int k0 = 0; k0 < K; k0 += 32) {
        GLDSF23(ga0 + k0, la0);
        GLDSF23(ga1 + k0, la1);
        GLDSF23(gb0 + k0, lb0);
        GLDSF23(gb1 + k0, lb1);
        __syncthreads();
        short8 af[4], bfr[4];
        #pragma unroll
        for (int i = 0; i < 4; ++i) af[i] = *(const short8*)&As[(wr * 64 + i * 16 + lr) * 32 + g * 8];
        #pragma unroll
        for (int j = 0; j < 4; ++j) bfr[j] = *(const short8*)&Bs[(wc * 64 + j * 16 + lr) * 32 + g * 8];
        #pragma unroll
        for (int i = 0; i < 4; ++i)
            #pragma unroll
            for (int j = 0; j < 4; ++j)
                acc[i][j] = __builtin_amdgcn_mfma_f32_16x16x32_bf16(af[i], bfr[j], acc[i][j], 0, 0, 0);
        __syncthreads();
    }

    // C/D layout (r4-verified): col = lane&15, row = (lane>>4)*4 + reg
    const int r0 = bm + wr * 64 + g * 4;
    const int c0 = bn + wc * 64 + lr;
    float* C = Cv + (long)blockIdx.z * sC;
    #pragma unroll
    for (int i = 0; i < 4; ++i)
        #pragma unroll
        for (int j = 0; j < 4; ++j)
            #pragma unroll
            for (int r = 0; r < 4; ++r) {
                long o = (long)(r0 + i * 16 + r) * ldc + (c0 + j * 16);
                if (epi == 4) C[o] += acc[i][j][r];
                else          C[o] = scale * acc[i][j][r];
            }
}

// ---------------------------------------------------------------------------
// G2 scalar fp32, 64x64 tile, 4x4 acc (proven r22 verbatim)
// ---------------------------------------------------------------------------
__global__ __launch_bounds__(256)
void sg2c_f23(const float* __restrict__ kmF, const void* __restrict__ gs,
              float* __restrict__ BmatF, const int* __restrict__ dflag)
{
    const int bf = *dflag;
    __shared__ float gst[32][65];
    __shared__ float kmt[64][33];
    const int b = blockIdx.z;
    const int c0 = blockIdx.x * 64, n0 = blockIdx.y * 64;
    const int tid = threadIdx.x;
    const int tx = tid & 15, ty = tid >> 4;
    float acc[4][4];
    #pragma unroll
    for (int i = 0; i < 4; ++i)
        #pragma unroll
        for (int j = 0; j < 4; ++j) acc[i][j] = 0.f;

    const int glc = tid & 63, grb = tid >> 6;
    const int klc = tid & 31, krb = tid >> 5;
    for (int l0 = 0; l0 < L_; l0 += 32) {
        #pragma unroll
        for (int kk = 0; kk < 8; ++kk) {
            int r = grb + 4 * kk;
            gst[r][glc] = ldin_f23(gs, (long)(l0 + r) * NB_ + n0 + glc, bf);
            int rr = krb + 8 * kk;
            kmt[rr][klc] = kmF[((long)b * HID_ + c0 + rr) * L_ + l0 + klc];
        }
        __syncthreads();
        #pragma unroll 8
        for (int kk = 0; kk < 32; ++kk) {
            float gv[4], kv[4];
            #pragma unroll
            for (int j = 0; j < 4; ++j) gv[j] = gst[kk][ty + 16 * j];
            #pragma unroll
            for (int i = 0; i < 4; ++i) kv[i] = kmt[tx + 16 * i][kk];
            #pragma unroll
            for (int i = 0; i < 4; ++i)
                #pragma unroll
                for (int j = 0; j < 4; ++j)
                    acc[i][j] += kv[i] * gv[j];
        }
        __syncthreads();
    }
    #pragma unroll
    for (int j = 0; j < 4; ++j)
        #pragma unroll
        for (int i = 0; i < 4; ++i)
            BmatF[((long)b * NB_ + n0 + ty + 16 * j) * HID_ + c0 + tx + 16 * i] = acc[i][j];
}

// ---------------------------------------------------------------------------
// hoisted score reductions (proven verbatim)
// ---------------------------------------------------------------------------
__global__ void kw_f23(const float* __restrict__ keysF,
                       const void* __restrict__ w_mu, const void* __restrict__ w_sg,
                       float* __restrict__ kwmu, float* __restrict__ kwsg,
                       const int* __restrict__ dflag)
{
    const int bf = *dflag;
    const int bh = blockIdx.x;
    const int b = bh >> 4, h = bh & 15;
    const int d = threadIdx.x;
    const float* kb = keysF + (long)b * NB_ * HID_ + h * 64 + d;
    float am = 0.f, as = 0.f;
    for (int n = 0; n < NB_; ++n) {
        float kv = kb[(long)n * HID_];
        am += ldin_f23(w_mu, n, bf) * kv;
        as += ldin_f23(w_sg, n, bf) * kv;
    }
    kwmu[(long)bh * 64 + d] = am;
    kwsg[(long)bh * 64 + d] = as;
}

// ---------------------------------------------------------------------------
// attention v3: per-wave n-split PV (16 FMA per n), LDS tree reduction.
// Same per-row mu/sq math as proven; PV sum order is 4-block pairwise.
// ---------------------------------------------------------------------------
__global__ __launch_bounds__(256)
void attn_f23(float* __restrict__ qh, const float* __restrict__ valsF,
              const float* __restrict__ kwmu, const float* __restrict__ kwsg,
              const void* __restrict__ bmu, const void* __restrict__ bsg,
              const int* __restrict__ dflag)
{
    const int bf = *dflag;
    __shared__ float bmuS[512], bvS[512];
    __shared__ float rST[512][20];              // 40KB, padded (16B-aligned rows)
    const int b = blockIdx.z, h = blockIdx.y;
    const int tid = threadIdx.x, wv = tid >> 6, lane = tid & 63;
    const int qbase = blockIdx.x * 16;

    for (int i = tid; i < 512; i += 256) {
        bmuS[i] = ldin_f23(bmu, i, bf);
        float s = ldin_f23(bsg, i, bf);
        bvS[i] = s * s;
    }
    __syncthreads();

    const float km = kwmu[((long)b * H_ + h) * 64 + lane];
    const float ks = kwsg[((long)b * H_ + h) * 64 + lane];

    // phase 1: this wave's 4 rows -> mu/sq -> r into rST[n][wv*4+j]
    float mu[4], sq[4];
    #pragma unroll
    for (int j = 0; j < 4; ++j) {
        const float* qrow = qh + ((long)b * Q_ + qbase + wv * 4 + j) * HID_ + h * 64;
        float qv = qrow[lane];
        float pm = qv * km, ps = qv * ks;
        #pragma unroll
        for (int off = 32; off > 0; off >>= 1) {
            pm += __shfl_xor(pm, off);
            ps += __shfl_xor(ps, off);
        }
        mu[j] = 1.f / (1.f + expf(-pm));
        float sp = (ps > 0.f) ? (ps + log1pf(expf(-ps))) : log1pf(expf(ps));
        sq[j] = fmaxf(sp, 1e-6f);
    }
    #pragma unroll
    for (int j = 0; j < 4; ++j) {
        #pragma unroll
        for (int jj = 0; jj < 8; ++jj) {
            int n = lane + 64 * jj;
            float var = sq[j] + bvS[n];
            float dd = mu[j] - bmuS[n];
            rST[n][wv * 4 + j] = expf(-0.5f * dd * dd / var)
                                 / sqrtf(6.283185307179586f * var);
        }
    }
    __syncthreads();

    // phase 2: PV — wave wv covers n in [wv*128, wv*128+128), ALL 16 rows
    const float* vb = valsF + (long)b * NB_ * HID_ + h * 64 + lane;
    float cd[16];
    #pragma unroll
    for (int r = 0; r < 16; ++r) cd[r] = 0.f;
    const int nbase = wv * 128;
    for (int i = 0; i < 128; ++i) {
        int n = nbase + i;
        float v = vb[(long)n * HID_];
        const f32x4 r0 = *(const f32x4*)&rST[n][0];
        const f32x4 r1 = *(const f32x4*)&rST[n][4];
        const f32x4 r2 = *(const f32x4*)&rST[n][8];
        const f32x4 r3 = *(const f32x4*)&rST[n][12];
        #pragma unroll
        for (int j = 0; j < 4; ++j) {
            cd[j]      += r0[j] * v;
            cd[4 + j]  += r1[j] * v;
            cd[8 + j]  += r2[j] * v;
            cd[12 + j] += r3[j] * v;
        }
    }
    __syncthreads();

    // phase 3: cross-wave reduction via LDS (aliases rST; 16KB needed)
    float* red = (float*)rST;
    #pragma unroll
    for (int r = 0; r < 16; ++r)
        red[((wv * 16) + r) * 64 + lane] = cd[r];
    __syncthreads();

    #pragma unroll
    for (int j = 0; j < 4; ++j) {
        int row = wv * 4 + j;
        float s = red[(0 * 16 + row) * 64 + lane]
                + red[(1 * 16 + row) * 64 + lane]
                + red[(2 * 16 + row) * 64 + lane]
                + red[(3 * 16 + row) * 64 + lane];
        qh[((long)b * Q_ + qbase + row) * HID_ + h * 64 + lane] = s;
    }
}

// ---------------------------------------------------------------------------
extern "C" void kernel_launch(void* const* d_in, const int* in_sizes, int n_in,
                              void* d_out, int out_size, void* d_ws, size_t ws_size,
                              hipStream_t stream)
{
    static const int SZ_INS[13] = {16777216,16777216,4194304,2048,1048576,1048576,
                                   1048576,1048576,512,512,1048576,512,512};
    bool mi = (n_in == 13);
    if (mi) for (int i = 0; i < 13; ++i) if (in_sizes[i] != SZ_INS[i]) { mi = false; break; }
    if (!mi) {
        beacon_f23<<<2048, 256, 0, stream>>>((float*)d_out, (long)out_size, 7777777.f);
        return;
    }

    const void* k_in  = d_in[0];
    const void* query = d_in[1];
    const void* wm_f  = d_in[2];
    const void* bmask = d_in[3];
    const void* wq_f  = d_in[4];
    const void* wk_f  = d_in[5];
    const void* wv_f  = d_in[6];
    const void* wo_f  = d_in[7];
    const void* w_mu  = d_in[8];
    const void* w_sg  = d_in[9];
    const void* gs_f  = d_in[10];
    const void* bmu   = d_in[11];
    const void* bsg   = d_in[12];

    char* ws = (char*)d_ws;
    size_t off = 0;
    auto alloc = [&](size_t bytes) { char* p = ws + off; off += (bytes + 255) & ~(size_t)255; return p; };
    const size_t MiB = 1048576;
    const long SBH = (long)NB_ * HID_;
    const long SQH = (long)Q_ * HID_;
    const long SHL = (long)HID_ * L_;
    int*   dflag = (int*)alloc(256);
    char*  RQ    = alloc(64 * MiB);          // wmask[0:8)+kT[8:40) -> qhF/ctxF
    char*  SC    = alloc(64 * MiB);          // scores/kmF -> qflat[0:32)+bmh[32:40)+bml[40:48) -> ctxh/ctxl
    char*  BK    = alloc(16 * MiB);          // BmatF -> keysF
    float* valsF = (float*)alloc(16 * MiB);  // vals -> woc (after attn)
    u16*   wqc   = (u16*)alloc((size_t)HID_ * HID_ * 2);
    u16*   wkc   = (u16*)alloc((size_t)HID_ * HID_ * 2);
    u16*   wvc   = (u16*)alloc((size_t)HID_ * HID_ * 2);
    float* kwmu  = (float*)alloc((size_t)B_ * H_ * 64 * 4);
    float* kwsg  = (float*)alloc((size_t)B_ * H_ * 64 * 4);
    if (ws_size < off) {
        beacon_f23<<<2048, 256, 0, stream>>>((float*)d_out, (long)out_size, 9999999.f);
        return;
    }
    u16*   wmask = (u16*)RQ;                     // [0, 8MiB)
    u16*   kTp   = (u16*)(RQ + 8 * MiB);         // [8, 40MiB)
    float* qhF   = (float*)RQ;                   // after G1/ew (wmask,kT dead)
    float* ctxF  = qhF;
    float* SCf   = (float*)SC;                   // scores -> kmF (in place)
    u16*   qflat = (u16*)SC;                     // [0, 32MiB)   after sg2c
    u16*   bmh   = (u16*)(SC + 32 * MiB);        // [32, 40MiB)
    u16*   bml   = (u16*)(SC + 40 * MiB);        // [40, 48MiB)
    u16*   ctxh  = (u16*)SC;                     // [0, 32MiB)   after attn
    u16*   ctxl  = (u16*)(SC + 32 * MiB);        // [32, 64MiB)
    float* BmatF = (float*)BK;
    float* keysF = (float*)BK;                   // after split (BmatF dead)
    u16*   woc   = (u16*)valsF;                  // after attn (valsF dead)

    probe_f23<<<1, 256, 0, stream>>>((const unsigned*)k_in, dflag);
    conv_f23<<<1024, 256, 0, stream>>>(wq_f, wqc, (long)HID_ * HID_, dflag);
    conv_f23<<<1024, 256, 0, stream>>>(wk_f, wkc, (long)HID_ * HID_, dflag);
    conv_f23<<<1024, 256, 0, stream>>>(wv_f, wvc, (long)HID_ * HID_, dflag);
    conv_f23<<<2048, 256, 0, stream>>>(wm_f, wmask, (long)L_ * L_, dflag);
    tr_f23<<<dim3(HID_ / 64, L_ / 64, B_), 256, 0, stream>>>(
        k_in, kTp, L_, HID_, (long)L_ * HID_, SHL, dflag);

    // G1a (MFMA, proven): SC = kT @ wmask^T  (fp32 scores)
    gemm_f23<<<dim3(L_ / 128, HID_ / 128, B_), 256, 0, stream>>>(
        kTp, L_, SHL, wmask, L_, 0, SCf, L_, SHL, L_, 1.f, 3);
    // G1b (proven): km = kT * sigmoid(SC + bmask)  (in place)
    ew_f23<<<2048, 256, 0, stream>>>(SCf, kTp, bmask, dflag);

    // G2 (scalar fp32, 64x64 tiles): BmatF = Gs^T @ km
    sg2c_f23<<<dim3(HID_ / 64, NB_ / 64, B_), 256, 0, stream>>>(SCf, gs_f, BmatF, dflag);
    // split Bmat -> bmh/bml (kmF dead; writes SC[32:48))
    split_f23<<<2048, 256, 0, stream>>>(BmatF, bmh, bml, (long)B_ * SBH);

    // qflat gather into SC[0:32)
    qg_f23<<<4096, 256, 0, stream>>>(query, qflat, dflag);
    // G5 (MFMA, proven): qhF = 0.125 * qflat @ Wq^T  (over RQ; wmask/kT dead)
    gemm_f23<<<dim3(HID_ / 128, Q_ / 128, B_), 256, 0, stream>>>(
        qflat, HID_, SQH, wqc, HID_, 0, qhF, HID_, SQH, HID_, 0.125f, 3);

    // G3 (MFMA 2-pass, proven): keysF = bmh@Wk^T += bml@Wk^T  (over dead BmatF)
    gemm_f23<<<dim3(HID_ / 128, NB_ / 128, B_), 256, 0, stream>>>(
        bmh, HID_, SBH, wkc, HID_, 0, keysF, HID_, SBH, HID_, 1.f, 3);
    gemm_f23<<<dim3(HID_ / 128, NB_ / 128, B_), 256, 0, stream>>>(
        bml, HID_, SBH, wkc, HID_, 0, keysF, HID_, SBH, HID_, 1.f, 4);
    kw_f23<<<B_ * H_, 64, 0, stream>>>(keysF, w_mu, w_sg, kwmu, kwsg, dflag);

    // G4 (MFMA 2-pass, proven): valsF = bmh@Wv^T += bml@Wv^T
    gemm_f23<<<dim3(HID_ / 128, NB_ / 128, B_), 256, 0, stream>>>(
        bmh, HID_, SBH, wvc, HID_, 0, valsF, HID_, SBH, HID_, 1.f, 3);
    gemm_f23<<<dim3(HID_ / 128, NB_ / 128, B_), 256, 0, stream>>>(
        bml, HID_, SBH, wvc, HID_, 0, valsF, HID_, SBH, HID_, 1.f, 4);

    // attention v3: ctx in place over qhF
    attn_f23<<<dim3(Q_ / 16, H_, B_), 256, 0, stream>>>(
        qhF, valsF, kwmu, kwsg, bmu, bsg, dflag);

    // G7 (MFMA 2-pass, proven): split ctx, out = ctxh@Wo^T += ctxl@Wo^T
    conv_f23<<<1024, 256, 0, stream>>>(wo_f, woc, (long)HID_ * HID_, dflag);
    split_f23<<<2048, 256, 0, stream>>>(ctxF, ctxh, ctxl, (long)B_ * SQH);
    gemm_f23<<<dim3(HID_ / 128, Q_ / 128, B_), 256, 0, stream>>>(
        ctxh, HID_, SQH, woc, HID_, 0, (float*)d_out, HID_, SQH, HID_, 1.f, 3);
    gemm_f23<<<dim3(HID_ / 128, Q_ / 128, B_), 256, 0, stream>>>(
        ctxl, HID_, SQH, woc, HID_, 0, (float*)d_out, HID_, SQH, HID_, 1.f, 4);
}

// Round 24
// 1325.779 us; speedup vs baseline: 1.2095x; 1.2095x over previous
//
#include <hip/hip_runtime.h>
#include <hip/hip_bf16.h>

#define L_   2048
#define NB_  512
#define HID_ 1024
#define H_   16
#define D_   64
#define B_   8
#define Q_   2048

typedef unsigned short u16;
typedef float  f32x4  __attribute__((ext_vector_type(4)));
typedef short  short8 __attribute__((ext_vector_type(8)));

__device__ __forceinline__ u16 f2b_g24(float x) {
    __hip_bfloat16 h = __float2bfloat16(x);
    union { __hip_bfloat16 h; u16 u; } cv; cv.h = h; return cv.u;
}
__device__ __forceinline__ float b2f_g24(u16 u) {
    union { u16 u; __hip_bfloat16 h; } cv; cv.u = u; return __bfloat162float(cv.h);
}
__device__ __forceinline__ float ldin_g24(const void* p, long i, int bf) {
    return bf ? b2f_g24(((const u16*)p)[i]) : ((const float*)p)[i];
}

#define GLDSG24(gp, lp) __builtin_amdgcn_global_load_lds( \
    (const __attribute__((address_space(1))) void*)(gp), \
    (__attribute__((address_space(3))) void*)(lp), 16, 0, 0)

// ---------------------------------------------------------------------------
__global__ void probe_g24(const unsigned* __restrict__ k, int* __restrict__ flag)
{
    __shared__ int cnt;
    if (threadIdx.x == 0) cnt = 0;
    __syncthreads();
    int c = 0;
    for (int i = threadIdx.x; i < 4096; i += 256) {
        unsigned e = (k[i] >> 7) & 0xFFu;
        if (e >= 100u && e <= 135u) c++;
    }
    atomicAdd(&cnt, c);
    __syncthreads();
    if (threadIdx.x == 0) *flag = (cnt > 2048) ? 1 : 0;
}

__global__ void beacon_g24(float* __restrict__ out, long n, float code)
{
    long i = (long)blockIdx.x * blockDim.x + threadIdx.x;
    long st = (long)gridDim.x * blockDim.x;
    for (; i < n; i += st) out[i] = 0.f;
    if (blockIdx.x == 0 && threadIdx.x == 0) out[0] = code;
}

// ---------------------------------------------------------------------------
__global__ void conv_g24(const void* __restrict__ in, u16* __restrict__ out,
                         long n, const int* __restrict__ dflag)
{
    const int bf = *dflag;
    long i = (long)blockIdx.x * blockDim.x + threadIdx.x;
    long st = (long)gridDim.x * blockDim.x;
    for (; i < n; i += st) out[i] = f2b_g24(ldin_g24(in, i, bf));
}

// query (B,H,Q,64) -> qflat (B,Q,HID) bf16
__global__ void qg_g24(const void* __restrict__ q, u16* __restrict__ out,
                       const int* __restrict__ dflag)
{
    const int bf = *dflag;
    const long n = (long)B_ * H_ * Q_ * D_;
    long i = (long)blockIdx.x * blockDim.x + threadIdx.x;
    long st = (long)gridDim.x * blockDim.x;
    for (; i < n; i += st) {
        long dd = i & 63; long t = i >> 6;
        long qq = t & (Q_ - 1); t >>= 11;
        long h = t & (H_ - 1); long b = t >> 4;
        out[(b * Q_ + qq) * HID_ + h * 64 + dd] = f2b_g24(ldin_g24(q, i, bf));
    }
}

// fp32 -> hi + lo residual (bf16)   [proven]
__global__ void split_g24(const float* __restrict__ in, u16* __restrict__ hi,
                          u16* __restrict__ lo, long n)
{
    long i = (long)blockIdx.x * blockDim.x + threadIdx.x;
    long st = (long)gridDim.x * blockDim.x;
    for (; i < n; i += st) {
        float v = in[i];
        u16 h = f2b_g24(v);
        hi[i] = h;
        lo[i] = f2b_g24(v - b2f_g24(h));
    }
}

// transpose (proven): in (R,C) raw -> out (C,R) bf16
__global__ __launch_bounds__(256)
void tr_g24(const void* __restrict__ in, u16* __restrict__ out,
            int R, int C, long sIn, long sOut, const int* __restrict__ dflag)
{
    const int bf = *dflag;
    __shared__ u16 t[64][66];
    const long ibase = (long)blockIdx.z * sIn;
    u16* ob = out + (long)blockIdx.z * sOut;
    const int r0 = blockIdx.y * 64, c0 = blockIdx.x * 64;
    const int lc = threadIdx.x & 63, rb = threadIdx.x >> 6;
    #pragma unroll
    for (int kk = 0; kk < 16; ++kk) {
        int r = rb * 16 + kk;
        t[r][lc] = f2b_g24(ldin_g24(in, ibase + (long)(r0 + r) * C + c0 + lc, bf));
    }
    __syncthreads();
    #pragma unroll
    for (int kk = 0; kk < 16; ++kk) {
        int cr = rb * 16 + kk;
        ob[(long)(c0 + cr) * R + r0 + lc] = t[lc][cr];
    }
}

// transpose + split: in (R,C) fp32 -> hi/lo (C,R) bf16   [r20 trsplit structure]
__global__ __launch_bounds__(256)
void trsplitv_g24(const float* __restrict__ in, u16* __restrict__ hi,
                  u16* __restrict__ lo, int R, int C, long sIn, long sOut)
{
    __shared__ float t[64][65];
    const float* ib = in + (long)blockIdx.z * sIn;
    u16* oh = hi + (long)blockIdx.z * sOut;
    u16* ol = lo + (long)blockIdx.z * sOut;
    const int r0 = blockIdx.y * 64, c0 = blockIdx.x * 64;
    const int lc = threadIdx.x & 63, rb = threadIdx.x >> 6;
    #pragma unroll
    for (int kk = 0; kk < 16; ++kk) {
        int r = rb * 16 + kk;
        t[r][lc] = ib[(long)(r0 + r) * C + c0 + lc];
    }
    __syncthreads();
    #pragma unroll
    for (int kk = 0; kk < 16; ++kk) {
        int cr = rb * 16 + kk;
        float v = t[lc][cr];
        u16 hh = f2b_g24(v);
        long o = (long)(c0 + cr) * R + r0 + lc;
        oh[o] = hh;
        ol[o] = f2b_g24(v - b2f_g24(hh));
    }
}

// elementwise mask epilogue (proven): km = kT * sigmoid(S + bmask), in place
__global__ void ew_g24(float* __restrict__ S, const u16* __restrict__ kT,
                       const void* __restrict__ bmask, const int* __restrict__ dflag)
{
    const int bf = *dflag;
    const long n = (long)B_ * HID_ * L_;
    long i = (long)blockIdx.x * blockDim.x + threadIdx.x;
    long st = (long)gridDim.x * blockDim.x;
    for (; i < n; i += st) {
        long m = i & (L_ - 1);
        float sg = 1.f / (1.f + expf(-(S[i] + ldin_g24(bmask, m, bf))));
        S[i] = b2f_g24(kT[i]) * sg;
    }
}

// ---------------------------------------------------------------------------
// MFMA GEMM (m97 structure, proven): C[M,N] = sum_k A[M,K]*Bt[N,K]
// epi: 3 = fp32 store (scale applied) ; 4 = fp32 accumulate
// ---------------------------------------------------------------------------
__global__ __launch_bounds__(256)
void gemm_g24(const u16* __restrict__ A, int lda, long sA,
              const u16* __restrict__ Bt, int ldb, long sB,
              float* __restrict__ Cv, int ldc, long sC, int K,
              float scale, int epi)
{
    __shared__ u16 As[128 * 32];
    __shared__ u16 Bs[128 * 32];
    const int tid = threadIdx.x;
    const int wv = tid >> 6, ln = tid & 63;
    const int g = ln >> 4, lr = ln & 15;
    const int wr = wv >> 1, wc = wv & 1;
    const int bm = blockIdx.y * 128, bn = blockIdx.x * 128;
    const u16* Ab = A + (long)blockIdx.z * sA;
    const u16* Bb = Bt + (long)blockIdx.z * sB;

    const int sr = ln >> 2;
    const int scl = (ln & 3) * 8;
    const u16* ga0 = Ab + (long)(bm + wv * 16 + sr) * lda + scl;
    const u16* ga1 = Ab + (long)(bm + (wv + 4) * 16 + sr) * lda + scl;
    const u16* gb0 = Bb + (long)(bn + wv * 16 + sr) * ldb + scl;
    const u16* gb1 = Bb + (long)(bn + (wv + 4) * 16 + sr) * ldb + scl;
    u16* la0 = &As[wv * 512];
    u16* la1 = &As[(wv + 4) * 512];
    u16* lb0 = &Bs[wv * 512];
    u16* lb1 = &Bs[(wv + 4) * 512];

    f32x4 acc[4][4];
    #pragma unroll
    for (int i = 0; i < 4; ++i)
        #pragma unroll
        for (int j = 0; j < 4; ++j) acc[i][j] = (f32x4){0.f, 0.f, 0.f, 0.f};

    for (int k0 = 0; k0 < K; k0 += 32) {
        GLDSG24(ga0 + k0, la0);
        GLDSG24(ga1 + k0, la1);
        GLDSG24(gb0 + k0, lb0);
        GLDSG24(gb1 + k0, lb1);
        __syncthreads();
        short8 af[4], bfr[4];
        #pragma unroll
        for (int i = 0; i < 4; ++i) af[i] = *(const short8*)&As[(wr * 64 + i * 16 + lr) * 32 + g * 8];
        #pragma unroll
        for (int j = 0; j < 4; ++j) bfr[j] = *(const short8*)&Bs[(wc * 64 + j * 16 + lr) * 32 + g * 8];
        #pragma unroll
        for (int i = 0; i < 4; ++i)
            #pragma unroll
            for (int j = 0; j < 4; ++j)
                acc[i][j] = __builtin_amdgcn_mfma_f32_16x16x32_bf16(af[i], bfr[j], acc[i][j], 0, 0, 0);
        __syncthreads();
    }

    // C/D layout (verified): col = lane&15, row = (lane>>4)*4 + reg
    const int r0 = bm + wr * 64 + g * 4;
    const int c0 = bn + wc * 64 + lr;
    float* C = Cv + (long)blockIdx.z * sC;
    #pragma unroll
    for (int i = 0; i < 4; ++i)
        #pragma unroll
        for (int j = 0; j < 4; ++j)
            #pragma unroll
            for (int r = 0; r < 4; ++r) {
                long o = (long)(r0 + i * 16 + r) * ldc + (c0 + j * 16);
                if (epi == 4) C[o] += acc[i][j][r];
                else          C[o] = scale * acc[i][j][r];
            }
}

// ---------------------------------------------------------------------------
// G2 scalar fp32, 64x64 tile, 4x4 acc (proven r22 verbatim)
// ---------------------------------------------------------------------------
__global__ __launch_bounds__(256)
void sg2c_g24(const float* __restrict__ kmF, const void* __restrict__ gs,
              float* __restrict__ BmatF, const int* __restrict__ dflag)
{
    const int bf = *dflag;
    __shared__ float gst[32][65];
    __shared__ float kmt[64][33];
    const int b = blockIdx.z;
    const int c0 = blockIdx.x * 64, n0 = blockIdx.y * 64;
    const int tid = threadIdx.x;
    const int tx = tid & 15, ty = tid >> 4;
    float acc[4][4];
    #pragma unroll
    for (int i = 0; i < 4; ++i)
        #pragma unroll
        for (int j = 0; j < 4; ++j) acc[i][j] = 0.f;

    const int glc = tid & 63, grb = tid >> 6;
    const int klc = tid & 31, krb = tid >> 5;
    for (int l0 = 0; l0 < L_; l0 += 32) {
        #pragma unroll
        for (int kk = 0; kk < 8; ++kk) {
            int r = grb + 4 * kk;
            gst[r][glc] = ldin_g24(gs, (long)(l0 + r) * NB_ + n0 + glc, bf);
            int rr = krb + 8 * kk;
            kmt[rr][klc] = kmF[((long)b * HID_ + c0 + rr) * L_ + l0 + klc];
        }
        __syncthreads();
        #pragma unroll 8
        for (int kk = 0; kk < 32; ++kk) {
            float gv[4], kv[4];
            #pragma unroll
            for (int j = 0; j < 4; ++j) gv[j] = gst[kk][ty + 16 * j];
            #pragma unroll
            for (int i = 0; i < 4; ++i) kv[i] = kmt[tx + 16 * i][kk];
            #pragma unroll
            for (int i = 0; i < 4; ++i)
                #pragma unroll
                for (int j = 0; j < 4; ++j)
                    acc[i][j] += kv[i] * gv[j];
        }
        __syncthreads();
    }
    #pragma unroll
    for (int j = 0; j < 4; ++j)
        #pragma unroll
        for (int i = 0; i < 4; ++i)
            BmatF[((long)b * NB_ + n0 + ty + 16 * j) * HID_ + c0 + tx + 16 * i] = acc[i][j];
}

// ---------------------------------------------------------------------------
// hoisted score reductions (proven verbatim)
// ---------------------------------------------------------------------------
__global__ void kw_g24(const float* __restrict__ keysF,
                       const void* __restrict__ w_mu, const void* __restrict__ w_sg,
                       float* __restrict__ kwmu, float* __restrict__ kwsg,
                       const int* __restrict__ dflag)
{
    const int bf = *dflag;
    const int bh = blockIdx.x;
    const int b = bh >> 4, h = bh & 15;
    const int d = threadIdx.x;
    const float* kb = keysF + (long)b * NB_ * HID_ + h * 64 + d;
    float am = 0.f, as = 0.f;
    for (int n = 0; n < NB_; ++n) {
        float kv = kb[(long)n * HID_];
        am += ldin_g24(w_mu, n, bf) * kv;
        as += ldin_g24(w_sg, n, bf) * kv;
    }
    kwmu[(long)bh * 64 + d] = am;
    kwsg[(long)bh * 64 + d] = as;
}

// ---------------------------------------------------------------------------
// attention v4: mu/sq as proven; r split to bf16 hi/lo per 64-n tile; PV via
// split-bf16 MFMA (hi*hi + hi*lo + lo*hi, fp32 acc), vals pre-split transposed.
// ---------------------------------------------------------------------------
__global__ __launch_bounds__(256)
void attn_g24(float* __restrict__ qh,
              const u16* __restrict__ vTh, const u16* __restrict__ vTl,
              const float* __restrict__ kwmu, const float* __restrict__ kwsg,
              const void* __restrict__ bmu, const void* __restrict__ bsg,
              const int* __restrict__ dflag)
{
    const int bf = *dflag;
    __shared__ float bmuS[512], bvS[512];
    __shared__ float mu_s[16], sq_s[16];
    __shared__ u16 rAh[16 * 80], rAl[16 * 80];     // [row][80] padded, 16B-aligned
    __shared__ u16 vBh[64 * 80], vBl[64 * 80];     // [d][80] padded
    const int b = blockIdx.z, h = blockIdx.y;
    const int tid = threadIdx.x, wv = tid >> 6, lane = tid & 63;
    const int qbase = blockIdx.x * 16;

    for (int i = tid; i < 512; i += 256) {
        bmuS[i] = ldin_g24(bmu, i, bf);
        float s = ldin_g24(bsg, i, bf);
        bvS[i] = s * s;
    }

    const float km = kwmu[((long)b * H_ + h) * 64 + lane];
    const float ks = kwsg[((long)b * H_ + h) * 64 + lane];

    // phase 1: wave wv -> mu/sq for rows wv*4..wv*4+3 (math as proven)
    #pragma unroll
    for (int j = 0; j < 4; ++j) {
        const float* qrow = qh + ((long)b * Q_ + qbase + wv * 4 + j) * HID_ + h * 64;
        float qv = qrow[lane];
        float pm = qv * km, ps = qv * ks;
        #pragma unroll
        for (int off = 32; off > 0; off >>= 1) {
            pm += __shfl_xor(pm, off);
            ps += __shfl_xor(ps, off);
        }
        if (lane == 0) {
            mu_s[wv * 4 + j] = 1.f / (1.f + expf(-pm));
            float sp = (ps > 0.f) ? (ps + log1pf(expf(-ps))) : log1pf(expf(ps));
            sq_s[wv * 4 + j] = fmaxf(sp, 1e-6f);
        }
    }
    __syncthreads();

    const int rrow = tid >> 4;            // 0..15
    const int rn0  = (tid & 15) * 4;      // 0..60
    const float muR = mu_s[rrow], sqR = sq_s[rrow];
    const int g = lane >> 4, lr = lane & 15;
    f32x4 acc = (f32x4){0.f, 0.f, 0.f, 0.f};

    for (int kt = 0; kt < 8; ++kt) {
        const int nbase = kt * 64;
        // r-compute + split (4 values per thread)
        #pragma unroll
        for (int i = 0; i < 4; ++i) {
            int n = rn0 + i;
            int N = nbase + n;
            float var = sqR + bvS[N];
            float dd = muR - bmuS[N];
            float rv = expf(-0.5f * dd * dd / var) * rsqrtf(6.2831853071795864f * var);
            u16 hh = f2b_g24(rv);
            rAh[rrow * 80 + n] = hh;
            rAl[rrow * 80 + n] = f2b_g24(rv - b2f_g24(hh));
        }
        // vals tile load (bf16 pre-split, transposed layout [d][n])
        #pragma unroll
        for (int j2 = 0; j2 < 2; ++j2) {
            int id = tid * 2 + j2;                     // 0..511
            int d = id >> 3, nb8 = id & 7;
            long go = ((long)b * HID_ + h * 64 + d) * NB_ + nbase + nb8 * 8;
            *(short8*)&vBh[d * 80 + nb8 * 8] = *(const short8*)(vTh + go);
            *(short8*)&vBl[d * 80 + nb8 * 8] = *(const short8*)(vTl + go);
        }
        __syncthreads();
        // MFMA: wave wv covers d-cols [wv*16, wv*16+16)
        #pragma unroll
        for (int kss = 0; kss < 2; ++kss) {
            short8 ah = *(const short8*)&rAh[lr * 80 + kss * 32 + g * 8];
            short8 al = *(const short8*)&rAl[lr * 80 + kss * 32 + g * 8];
            short8 bh = *(const short8*)&vBh[(wv * 16 + lr) * 80 + kss * 32 + g * 8];
            short8 bl = *(const short8*)&vBl[(wv * 16 + lr) * 80 + kss * 32 + g * 8];
            acc = __builtin_amdgcn_mfma_f32_16x16x32_bf16(ah, bh, acc, 0, 0, 0);
            acc = __builtin_amdgcn_mfma_f32_16x16x32_bf16(ah, bl, acc, 0, 0, 0);
            acc = __builtin_amdgcn_mfma_f32_16x16x32_bf16(al, bh, acc, 0, 0, 0);
        }
        __syncthreads();
    }

    // epilogue (verified C/D layout): row = g*4 + r, col = lr
    #pragma unroll
    for (int r = 0; r < 4; ++r) {
        int row = g * 4 + r;
        qh[((long)b * Q_ + qbase + row) * HID_ + h * 64 + wv * 16 + lr] = acc[r];
    }
}

// ---------------------------------------------------------------------------
extern "C" void kernel_launch(void* const* d_in, const int* in_sizes, int n_in,
                              void* d_out, int out_size, void* d_ws, size_t ws_size,
                              hipStream_t stream)
{
    static const int SZ_INS[13] = {16777216,16777216,4194304,2048,1048576,1048576,
                                   1048576,1048576,512,512,1048576,512,512};
    bool mi = (n_in == 13);
    if (mi) for (int i = 0; i < 13; ++i) if (in_sizes[i] != SZ_INS[i]) { mi = false; break; }
    if (!mi) {
        beacon_g24<<<2048, 256, 0, stream>>>((float*)d_out, (long)out_size, 7777777.f);
        return;
    }

    const void* k_in  = d_in[0];
    const void* query = d_in[1];
    const void* wm_f  = d_in[2];
    const void* bmask = d_in[3];
    const void* wq_f  = d_in[4];
    const void* wk_f  = d_in[5];
    const void* wv_f  = d_in[6];
    const void* wo_f  = d_in[7];
    const void* w_mu  = d_in[8];
    const void* w_sg  = d_in[9];
    const void* gs_f  = d_in[10];
    const void* bmu   = d_in[11];
    const void* bsg   = d_in[12];

    char* ws = (char*)d_ws;
    size_t off = 0;
    auto alloc = [&](size_t bytes) { char* p = ws + off; off += (bytes + 255) & ~(size_t)255; return p; };
    const size_t MiB = 1048576;
    const long SBH = (long)NB_ * HID_;
    const long SQH = (long)Q_ * HID_;
    const long SHL = (long)HID_ * L_;
    int*   dflag = (int*)alloc(256);
    char*  RQ    = alloc(64 * MiB);          // wmask[0:8)+kT[8:40) -> qhF/ctxF
    char*  SC    = alloc(64 * MiB);          // scores/kmF -> qflat[0:32)+bmh[32:40)+bml[40:48) -> ctxh/ctxl
    char*  BK    = alloc(16 * MiB);          // BmatF -> keysF -> vTh[0:8)+vTl[8:16)
    float* valsF = (float*)alloc(16 * MiB);  // vals -> woc (after trsplitv)
    u16*   wqc   = (u16*)alloc((size_t)HID_ * HID_ * 2);
    u16*   wkc   = (u16*)alloc((size_t)HID_ * HID_ * 2);
    u16*   wvc   = (u16*)alloc((size_t)HID_ * HID_ * 2);
    float* kwmu  = (float*)alloc((size_t)B_ * H_ * 64 * 4);
    float* kwsg  = (float*)alloc((size_t)B_ * H_ * 64 * 4);
    if (ws_size < off) {
        beacon_g24<<<2048, 256, 0, stream>>>((float*)d_out, (long)out_size, 9999999.f);
        return;
    }
    u16*   wmask = (u16*)RQ;                     // [0, 8MiB)
    u16*   kTp   = (u16*)(RQ + 8 * MiB);         // [8, 40MiB)
    float* qhF   = (float*)RQ;                   // after G1/ew (wmask,kT dead)
    float* ctxF  = qhF;
    float* SCf   = (float*)SC;                   // scores -> kmF (in place)
    u16*   qflat = (u16*)SC;                     // [0, 32MiB)   after sg2c
    u16*   bmh   = (u16*)(SC + 32 * MiB);        // [32, 40MiB)
    u16*   bml   = (u16*)(SC + 40 * MiB);        // [40, 48MiB)
    u16*   ctxh  = (u16*)SC;                     // [0, 32MiB)   after attn
    u16*   ctxl  = (u16*)(SC + 32 * MiB);        // [32, 64MiB)
    float* BmatF = (float*)BK;
    float* keysF = (float*)BK;                   // after split (BmatF dead)
    u16*   vTh   = (u16*)BK;                     // [0, 8MiB)  after kw (keysF dead)
    u16*   vTl   = (u16*)(BK + 8 * MiB);         // [8, 16MiB)
    u16*   woc   = (u16*)valsF;                  // after trsplitv (valsF dead)

    probe_g24<<<1, 256, 0, stream>>>((const unsigned*)k_in, dflag);
    conv_g24<<<1024, 256, 0, stream>>>(wq_f, wqc, (long)HID_ * HID_, dflag);
    conv_g24<<<1024, 256, 0, stream>>>(wk_f, wkc, (long)HID_ * HID_, dflag);
    conv_g24<<<1024, 256, 0, stream>>>(wv_f, wvc, (long)HID_ * HID_, dflag);
    conv_g24<<<2048, 256, 0, stream>>>(wm_f, wmask, (long)L_ * L_, dflag);
    tr_g24<<<dim3(HID_ / 64, L_ / 64, B_), 256, 0, stream>>>(
        k_in, kTp, L_, HID_, (long)L_ * HID_, SHL, dflag);

    // G1a (MFMA, proven): SC = kT @ wmask^T  (fp32 scores)
    gemm_g24<<<dim3(L_ / 128, HID_ / 128, B_), 256, 0, stream>>>(
        kTp, L_, SHL, wmask, L_, 0, SCf, L_, SHL, L_, 1.f, 3);
    // G1b (proven): km = kT * sigmoid(SC + bmask)  (in place)
    ew_g24<<<2048, 256, 0, stream>>>(SCf, kTp, bmask, dflag);

    // G2 (scalar fp32, 64x64 tiles): BmatF = Gs^T @ km
    sg2c_g24<<<dim3(HID_ / 64, NB_ / 64, B_), 256, 0, stream>>>(SCf, gs_f, BmatF, dflag);
    // split Bmat -> bmh/bml (kmF dead; writes SC[32:48))
    split_g24<<<2048, 256, 0, stream>>>(BmatF, bmh, bml, (long)B_ * SBH);

    // qflat gather into SC[0:32)
    qg_g24<<<4096, 256, 0, stream>>>(query, qflat, dflag);
    // G5 (MFMA, proven): qhF = 0.125 * qflat @ Wq^T  (over RQ; wmask/kT dead)
    gemm_g24<<<dim3(HID_ / 128, Q_ / 128, B_), 256, 0, stream>>>(
        qflat, HID_, SQH, wqc, HID_, 0, qhF, HID_, SQH, HID_, 0.125f, 3);

    // G3 (MFMA 2-pass, proven): keysF = bmh@Wk^T += bml@Wk^T  (over dead BmatF)
    gemm_g24<<<dim3(HID_ / 128, NB_ / 128, B_), 256, 0, stream>>>(
        bmh, HID_, SBH, wkc, HID_, 0, keysF, HID_, SBH, HID_, 1.f, 3);
    gemm_g24<<<dim3(HID_ / 128, NB_ / 128, B_), 256, 0, stream>>>(
        bml, HID_, SBH, wkc, HID_, 0, keysF, HID_, SBH, HID_, 1.f, 4);
    kw_g24<<<B_ * H_, 64, 0, stream>>>(keysF, w_mu, w_sg, kwmu, kwsg, dflag);

    // G4 (MFMA 2-pass, proven): valsF = bmh@Wv^T += bml@Wv^T
    gemm_g24<<<dim3(HID_ / 128, NB_ / 128, B_), 256, 0, stream>>>(
        bmh, HID_, SBH, wvc, HID_, 0, valsF, HID_, SBH, HID_, 1.f, 3);
    gemm_g24<<<dim3(HID_ / 128, NB_ / 128, B_), 256, 0, stream>>>(
        bml, HID_, SBH, wvc, HID_, 0, valsF, HID_, SBH, HID_, 1.f, 4);

    // transpose+split vals: (B, NB, HID) fp32 -> (B, HID, NB) bf16 hi/lo
    // (over BK region; keysF consumed by kw above)
    trsplitv_g24<<<dim3(HID_ / 64, NB_ / 64, B_), 256, 0, stream>>>(
        valsF, vTh, vTl, NB_, HID_, SBH, SBH);

    // attention v4 (MFMA PV): ctx in place over qhF
    attn_g24<<<dim3(Q_ / 16, H_, B_), 256, 0, stream>>>(
        qhF, vTh, vTl, kwmu, kwsg, bmu, bsg, dflag);

    // G7 (MFMA 2-pass, proven): split ctx, out = ctxh@Wo^T += ctxl@Wo^T
    conv_g24<<<1024, 256, 0, stream>>>(wo_f, woc, (long)HID_ * HID_, dflag);
    split_g24<<<2048, 256, 0, stream>>>(ctxF, ctxh, ctxl, (long)B_ * SQH);
    gemm_g24<<<dim3(HID_ / 128, Q_ / 128, B_), 256, 0, stream>>>(
        ctxh, HID_, SQH, woc, HID_, 0, (float*)d_out, HID_, SQH, HID_, 1.f, 3);
    gemm_g24<<<dim3(HID_ / 128, Q_ / 128, B_), 256, 0, stream>>>(
        ctxl, HID_, SQH, woc, HID_, 0, (float*)d_out, HID_, SQH, HID_, 1.f, 4);
}